// Round 7
// baseline (235.655 us; speedup 1.0000x reference)
//
#include <hip/hip_runtime.h>

#define Bsz 16
#define Tsz 4096
#define Dsz 512
#define Ksz 256
#define Msz (Bsz * Tsz)      // 65536
#define CHUNK 64
#define NCH (Tsz / CHUNK)    // 64

typedef __attribute__((ext_vector_type(8))) short short8;
typedef __attribute__((ext_vector_type(4))) float f32x4;
typedef __attribute__((ext_vector_type(4))) unsigned int u32x4;

// ---------------- threefry2x32 (key = (0, 42)) — matches JAX exactly -------
__device__ __forceinline__ unsigned int rotl32(unsigned int x, int d) {
  return (x << d) | (x >> (32 - d));
}

__device__ void threefry_pair(unsigned int c0, unsigned int c1,
                              unsigned int& o0, unsigned int& o1) {
  const unsigned int k0 = 0u, k1 = 42u;
  const unsigned int k2 = k0 ^ k1 ^ 0x1BD11BDAu;
  unsigned int x0 = c0 + k0;
  unsigned int x1 = c1 + k1;
#define TF_ROUND(r) { x0 += x1; x1 = rotl32(x1, (r)); x1 ^= x0; }
  TF_ROUND(13) TF_ROUND(15) TF_ROUND(26) TF_ROUND(6)
  x0 += k1; x1 += k2 + 1u;
  TF_ROUND(17) TF_ROUND(29) TF_ROUND(16) TF_ROUND(24)
  x0 += k2; x1 += k0 + 2u;
  TF_ROUND(13) TF_ROUND(15) TF_ROUND(26) TF_ROUND(6)
  x0 += k0; x1 += k1 + 3u;
  TF_ROUND(17) TF_ROUND(29) TF_ROUND(16) TF_ROUND(24)
  x0 += k1; x1 += k2 + 4u;
  TF_ROUND(13) TF_ROUND(15) TF_ROUND(26) TF_ROUND(6)
  x0 += k2; x1 += k0 + 5u;
#undef TF_ROUND
  o0 = x0; o1 = x1;
}

// XLA ErfInv32 polynomial (math.cc)
__device__ float erfinv32(float x) {
  float w = -log1pf(-x * x);
  float p;
  if (w < 5.f) {
    w -= 2.5f;
    p = 2.81022636e-08f;
    p = fmaf(p, w, 3.43273939e-07f);
    p = fmaf(p, w, -3.5233877e-06f);
    p = fmaf(p, w, -4.39150654e-06f);
    p = fmaf(p, w, 0.00021858087f);
    p = fmaf(p, w, -0.00125372503f);
    p = fmaf(p, w, -0.00417768164f);
    p = fmaf(p, w, 0.246640727f);
    p = fmaf(p, w, 1.50140941f);
  } else {
    w = sqrtf(w) - 3.f;
    p = -0.000200214257f;
    p = fmaf(p, w, 0.000100950558f);
    p = fmaf(p, w, 0.00134934322f);
    p = fmaf(p, w, -0.00367342844f);
    p = fmaf(p, w, 0.00573950773f);
    p = fmaf(p, w, -0.0076224613f);
    p = fmaf(p, w, 0.00943887047f);
    p = fmaf(p, w, 1.00167406f);
    p = fmaf(p, w, 2.83297682f);
  }
  return p * x;
}

// JAX: bits -> uniform[-0.99999994, 1) -> sqrt(2)*erfinv
__device__ float bits_to_normal(unsigned int bits) {
  unsigned int fb = (bits >> 9) | 0x3f800000u;
  float f = __uint_as_float(fb) - 1.0f;   // [0,1)
  const float lo = -0.99999994f;          // nextafter(-1, 0) in f32
  float u = f * 2.0f + lo;                // hi - lo rounds to exactly 2.0f
  u = fmaxf(lo, u);
  return 1.41421356f * erfinv32(u);
}

__device__ float block_sum_512(float v, float* s_red) {
  #pragma unroll
  for (int o = 32; o > 0; o >>= 1) v += __shfl_down(v, o);
  const int lane = threadIdx.x & 63, wid = threadIdx.x >> 6;
  if (lane == 0) s_red[wid] = v;
  __syncthreads();
  float r = 0.f;
  #pragma unroll
  for (int i = 0; i < 8; ++i) r += s_red[i];
  __syncthreads();
  return r;
}

__device__ __forceinline__ unsigned int bf16rne(float f) {
  unsigned int u = __float_as_uint(f);
  return (u + 0x7FFFu + ((u >> 16) & 1u)) >> 16;
}

// --------- prep1 (16 blocks x 512): partial_v[b][d] = sum_k W[k][d]*u0n[k] --
__global__ __launch_bounds__(512) void prep1_kernel(
    const float* __restrict__ W, float* __restrict__ partial_v) {
  __shared__ float s_u0[Ksz];
  __shared__ float s_red[8];
  const int tid = threadIdx.x;
  if (tid < 128) {
    unsigned int y0, y1;
    threefry_pair((unsigned int)tid, (unsigned int)(tid + 128), y0, y1);
    s_u0[tid] = bits_to_normal(y0);
    s_u0[tid + 128] = bits_to_normal(y1);
  }
  __syncthreads();
  float val = (tid < Ksz) ? s_u0[tid] * s_u0[tid] : 0.f;
  float ss = block_sum_512(val, s_red);
  float inv = 1.f / fmaxf(sqrtf(ss), 1e-7f);

  const int k0 = blockIdx.x * 16;
  float acc = 0.f;
  #pragma unroll
  for (int kk = 0; kk < 16; ++kk)
    acc = fmaf(W[(size_t)(k0 + kk) * Dsz + tid], s_u0[k0 + kk], acc);
  partial_v[blockIdx.x * Dsz + tid] = acc * inv;
}

// --------- prep2 (64 blocks x 512): v = normalize(sum partials); wv rows ---
__global__ __launch_bounds__(512) void prep2_kernel(
    const float* __restrict__ W, const float* __restrict__ partial_v,
    float* __restrict__ wv) {
  __shared__ float s_v[Dsz];
  __shared__ float s_red[8];
  __shared__ float s_p[8];
  const int tid = threadIdx.x;
  float acc = 0.f;
  #pragma unroll
  for (int b = 0; b < 16; ++b) acc += partial_v[b * Dsz + tid];
  float ssv = block_sum_512(acc * acc, s_red);
  float invv = 1.f / fmaxf(sqrtf(ssv), 1e-7f);
  s_v[tid] = acc * invv;
  __syncthreads();

  // 4 rows per block, 128 threads per row
  const int k = blockIdx.x * 4 + (tid >> 7);
  const int sub = tid & 127;
  const float* wr = W + (size_t)k * Dsz;
  float p = 0.f;
  #pragma unroll
  for (int j = sub; j < Dsz; j += 128) p = fmaf(wr[j], s_v[j], p);
  #pragma unroll
  for (int o = 32; o > 0; o >>= 1) p += __shfl_down(p, o);
  const int lane = tid & 63, wid = tid >> 6;
  if (lane == 0) s_p[wid] = p;
  __syncthreads();
  if (tid < 4) wv[blockIdx.x * 4 + tid] = s_p[2 * tid] + s_p[2 * tid + 1];
}

// --------- prep3 (1 block x 256): sigma + all per-k constants --------------
// consts layout (floats): [0]=ar [K]=ai [2K]=A64r [3K]=A64i [4K]=P4r [5K]=P4i
//                         [6K]=P8r [7K]=P8i [8K]=P16r [9K]=P16i [10K]=inv_sigma
__global__ __launch_bounds__(256) void prep3_kernel(
    const float* __restrict__ s_real_raw, const float* __restrict__ s_imag,
    const float* __restrict__ tau_raw, const float* __restrict__ wv,
    float* __restrict__ consts) {
  __shared__ float s_p[4];
  const int tid = threadIdx.x;
  float v = wv[tid];
  float v2 = v * v;
  #pragma unroll
  for (int o = 32; o > 0; o >>= 1) v2 += __shfl_down(v2, o);
  const int lane = tid & 63, wid = tid >> 6;
  if (lane == 0) s_p[wid] = v2;
  __syncthreads();
  float sswv = s_p[0] + s_p[1] + s_p[2] + s_p[3];
  float sigma = sswv / fmaxf(sqrtf(sswv), 1e-7f);
  if (tid == 0) consts[10 * Ksz] = 1.f / sigma;

  float tr = tau_raw[0];
  float tau = fmaxf(tr, 0.f) + log1pf(expf(-fabsf(tr))) + 1e-3f;
  float srr = s_real_raw[tid];
  float sp = fmaxf(srr, 0.f) + log1pf(expf(-fabsf(srr)));
  float alpha0 = (sp + 1e-6f) * tau;
  float omega0 = s_imag[tid] * tau;
  const float dt = 1.f / 4095.f;
  float ad = alpha0 * dt, an = omega0 * dt;
  consts[tid]            = expf(-ad) * cosf(an);
  consts[Ksz + tid]      = expf(-ad) * sinf(an);
  consts[2 * Ksz + tid]  = expf(-ad * 64.f) * cosf(an * 64.f);
  consts[3 * Ksz + tid]  = expf(-ad * 64.f) * sinf(an * 64.f);
  consts[4 * Ksz + tid]  = expf(-ad * 4.f) * cosf(an * 4.f);
  consts[5 * Ksz + tid]  = expf(-ad * 4.f) * sinf(an * 4.f);
  consts[6 * Ksz + tid]  = expf(-ad * 8.f) * cosf(an * 8.f);
  consts[7 * Ksz + tid]  = expf(-ad * 8.f) * sinf(an * 8.f);
  consts[8 * Ksz + tid]  = expf(-ad * 16.f) * cosf(an * 16.f);
  consts[9 * Ksz + tid]  = expf(-ad * 16.f) * sinf(an * 16.f);
}

// --------- wpack: W/sigma -> bf16 h/l in MFMA B-fragment order -------------
__global__ __launch_bounds__(64) void wpack_kernel(
    const float* __restrict__ W, const float* __restrict__ consts,
    unsigned int* __restrict__ WfH, unsigned int* __restrict__ WfL) {
  const int kb = blockIdx.x >> 4;
  const int nb = blockIdx.x & 15;
  const int lane = threadIdx.x;
  const int lr = lane & 15, lg = lane >> 4;
  const float inv_sigma = consts[10 * Ksz];
  const float* src = W + (size_t)(nb * 16 + lr) * Dsz + kb * 32 + lg * 8;
  float v[8];
  *(float4*)&v[0] = *(const float4*)src;
  *(float4*)&v[4] = *(const float4*)(src + 4);
  unsigned int hh[4], ll[4];
  #pragma unroll
  for (int i = 0; i < 4; ++i) {
    float v0 = v[2 * i] * inv_sigma, v1 = v[2 * i + 1] * inv_sigma;
    unsigned int u0 = __float_as_uint(v0);
    unsigned int u1 = __float_as_uint(v1);
    hh[i] = (u0 >> 16) | (u1 & 0xFFFF0000u);
    float r0 = v0 - __uint_as_float(u0 & 0xFFFF0000u);
    float r1 = v1 - __uint_as_float(u1 & 0xFFFF0000u);
    ll[i] = bf16rne(r0) | (bf16rne(r1) << 16);
  }
  const size_t off = (size_t)blockIdx.x * 256 + lane * 4;   // in uints
  *(int4*)(WfH + off) = *(int4*)hh;
  *(int4*)(WfL + off) = *(int4*)ll;
}

// --------- MFMA GEMM + fused chunk-scan carry ------------------------------
// BM=64 (= one scan chunk), BN=256, BK=32, 256 thr = 4 waves (wn 0..3).
// NO LDS, NO barriers: A fragments loaded DIRECTLY from row-major f32 global
// (wave pattern = 16 rows x 128 contiguous B -> full-line coalescing),
// converted f32->bf16 h/l in-register. A raw dbuf 2-deep (HBM latency),
// B frag dbuf 1-ahead (L2). Waves run free; MFMA pipe | VALU overlap across
// the 2 resident waves/SIMD. Bit-identical U vs rounds 4-6.
__global__ __launch_bounds__(256, 2) void gemm_mfma(
    const float* __restrict__ X, const unsigned int* __restrict__ WfH,
    const unsigned int* __restrict__ WfL, const float* __restrict__ bias,
    const float* __restrict__ consts, float* __restrict__ U,
    float* __restrict__ carry) {
  const int tid = threadIdx.x;
  const size_t m0 = (size_t)blockIdx.x * 64;

  const int lane = tid & 63;
  const int wn = tid >> 6;
  const int lr = lane & 15;
  const int lg = lane >> 4;

  // A frag source: lane (lr,lg), tile (mf,kb) reads
  //   X[m0 + mf*16 + lr][kb*32 + lg*8 .. +8]
  const float* gxa = X + (m0 + lr) * Dsz + lg * 8;

  float xa0[4][8], xa1[4][8];           // raw A, 2-deep
  #define LOAD_A(dst, kb) do {                                               \
    _Pragma("unroll")                                                        \
    for (int mf = 0; mf < 4; ++mf) {                                         \
      const float* p = gxa + mf * (16 * Dsz) + (kb) * 32;                    \
      *(float4*)&dst[mf][0] = *(const float4*)p;                             \
      *(float4*)&dst[mf][4] = *(const float4*)(p + 4);                       \
    }                                                                        \
  } while (0)

  const char* const wfh = (const char*)WfH + (size_t)wn * 4096 + lane * 16;
  const char* const wfl = (const char*)WfL + (size_t)wn * 4096 + lane * 16;

  short8 bh0[4], bl0[4], bh1[4], bl1[4];
  #define LOAD_B(bh_, bl_, kb) do {                                          \
    const size_t tb = (size_t)(kb) * 16384;                                  \
    _Pragma("unroll")                                                        \
    for (int f = 0; f < 4; ++f) {                                            \
      bh_[f] = *(const short8*)(wfh + tb + (size_t)f * 1024);                \
      bl_[f] = *(const short8*)(wfl + tb + (size_t)f * 1024);                \
    }                                                                        \
  } while (0)

  short8 ah[4], al[4];                  // current A fragments (h/l)
  #define CONVERT(xa) do {                                                   \
    _Pragma("unroll")                                                        \
    for (int mf = 0; mf < 4; ++mf) {                                         \
      unsigned int hh[4], llw[4];                                            \
      _Pragma("unroll")                                                      \
      for (int i = 0; i < 4; ++i) {                                          \
        float v0 = xa[mf][2 * i], v1 = xa[mf][2 * i + 1];                    \
        unsigned int u0 = __float_as_uint(v0);                               \
        unsigned int u1 = __float_as_uint(v1);                               \
        hh[i] = (u0 >> 16) | (u1 & 0xFFFF0000u);                             \
        float r0 = v0 - __uint_as_float(u0 & 0xFFFF0000u);                   \
        float r1 = v1 - __uint_as_float(u1 & 0xFFFF0000u);                   \
        llw[i] = bf16rne(r0) | (bf16rne(r1) << 16);                          \
      }                                                                      \
      u32x4 th = {hh[0], hh[1], hh[2], hh[3]};                               \
      u32x4 tl = {llw[0], llw[1], llw[2], llw[3]};                           \
      ah[mf] = __builtin_bit_cast(short8, th);                               \
      al[mf] = __builtin_bit_cast(short8, tl);                               \
    }                                                                        \
  } while (0)

  f32x4 acc[4][4];
  #pragma unroll
  for (int i = 0; i < 4; ++i)
    #pragma unroll
    for (int j = 0; j < 4; ++j) acc[i][j] = (f32x4)(0.f);

  #define MFMA48(bh_, bl_) do {                                              \
    _Pragma("unroll")                                                        \
    for (int mf = 0; mf < 4; ++mf)                                           \
      _Pragma("unroll")                                                      \
      for (int nf = 0; nf < 4; ++nf)                                         \
        acc[mf][nf] = __builtin_amdgcn_mfma_f32_16x16x32_bf16(               \
            ah[mf], bh_[nf], acc[mf][nf], 0, 0, 0);                          \
    _Pragma("unroll")                                                        \
    for (int mf = 0; mf < 4; ++mf)                                           \
      _Pragma("unroll")                                                      \
      for (int nf = 0; nf < 4; ++nf)                                         \
        acc[mf][nf] = __builtin_amdgcn_mfma_f32_16x16x32_bf16(               \
            ah[mf], bl_[nf], acc[mf][nf], 0, 0, 0);                          \
    _Pragma("unroll")                                                        \
    for (int mf = 0; mf < 4; ++mf)                                           \
      _Pragma("unroll")                                                      \
      for (int nf = 0; nf < 4; ++nf)                                         \
        acc[mf][nf] = __builtin_amdgcn_mfma_f32_16x16x32_bf16(               \
            al[mf], bh_[nf], acc[mf][nf], 0, 0, 0);                          \
  } while (0)

  // prologue
  LOAD_A(xa0, 0);
  LOAD_A(xa1, 1);
  LOAD_B(bh0, bl0, 0);

  // steady state: body kb converts xa(kb) (landed 2 iters ago), reloads it
  // with kb+2, prefetches B(kb+1), then MFMAs tile kb.
  for (int kb = 0; kb < 14; kb += 2) {
    CONVERT(xa0);
    LOAD_A(xa0, kb + 2);
    LOAD_B(bh1, bl1, kb + 1);
    MFMA48(bh0, bl0);

    CONVERT(xa1);
    LOAD_A(xa1, kb + 3);
    LOAD_B(bh0, bl0, kb + 2);
    MFMA48(bh1, bl1);
  }
  // kb = 14
  CONVERT(xa0);
  LOAD_B(bh1, bl1, 15);
  MFMA48(bh0, bl0);
  // kb = 15
  CONVERT(xa1);
  MFMA48(bh1, bl1);

  #undef MFMA48
  #undef CONVERT
  #undef LOAD_B
  #undef LOAD_A

  // ---- epilogue: U store + fused chunk carry ----
  // u_t at t = mf*16 + lg*4 + j; weight a^{63-t} = P4^{3-lg} * P16^{3-mf} * a^{3-j}
  #pragma unroll
  for (int nf = 0; nf < 4; ++nf) {
    const int n = wn * 64 + nf * 16 + lr;
    const float bv = bias[n];
    const float ar_ = consts[n],           ai_ = consts[Ksz + n];
    const float p4r = consts[4 * Ksz + n], p4i = consts[5 * Ksz + n];
    const float p8r = consts[6 * Ksz + n], p8i = consts[7 * Ksz + n];
    const float p16r = consts[8 * Ksz + n], p16i = consts[9 * Ksz + n];
    const int e = 3 - lg;
    const float b1r = (e & 1) ? p4r : 1.f, b1i = (e & 1) ? p4i : 0.f;
    const float b2r = (e & 2) ? p8r : 1.f, b2i = (e & 2) ? p8i : 0.f;
    float wr = b1r * b2r - b1i * b2i;
    float wi = b1r * b2i + b1i * b2r;
    float Sr = 0.f, Si = 0.f;
    #pragma unroll
    for (int mf = 3; mf >= 0; --mf) {
      float vr = wr, vi = wi;
      #pragma unroll
      for (int j = 3; j >= 0; --j) {
        const float u = acc[mf][nf][j] + bv;
        U[(m0 + mf * 16 + lg * 4 + j) * Ksz + n] = u;
        Sr = fmaf(u, vr, Sr);
        Si = fmaf(u, vi, Si);
        if (j) {
          float t_ = vr * ar_ - vi * ai_;
          vi = vr * ai_ + vi * ar_;
          vr = t_;
        }
      }
      if (mf) {
        float t_ = wr * p16r - wi * p16i;
        wi = wr * p16i + wi * p16r;
        wr = t_;
      }
    }
    Sr += __shfl_xor(Sr, 16); Si += __shfl_xor(Si, 16);
    Sr += __shfl_xor(Sr, 32); Si += __shfl_xor(Si, 32);
    if (lg == 0)
      ((float2*)carry)[(size_t)blockIdx.x * Ksz + n] = make_float2(Sr, Si);
  }
}

// --------- scan pass 2: exclusive prefix over chunks (A = a^64) ------------
__global__ __launch_bounds__(64) void scan_prefix(
    const float* __restrict__ consts, const float* __restrict__ carry,
    float* __restrict__ prefix) {
  const int k = blockIdx.y * 64 + threadIdx.x;
  const int b = blockIdx.x;
  const float Ar = consts[2 * Ksz + k], Ai = consts[3 * Ksz + k];
  const float2* cp = (const float2*)carry;
  float2* pp = (float2*)prefix;
  float c = 0.f, s = 0.f;
  for (int m = 0; m < NCH; ++m) {
    const size_t idx = (size_t)(b * NCH + m) * Ksz + k;
    pp[idx] = make_float2(c, s);
    float2 L = cp[idx];
    float cn = fmaf(Ar, c, fmaf(-Ai, s, L.x));
    float sn = fmaf(Ai, c, fmaf(Ar, s, L.y));
    c = cn; s = sn;
  }
}

// --------- scan pass 3: rescan chunk from true carry, write output ---------
__global__ __launch_bounds__(256) void scan_final(
    const float* __restrict__ U, const float* __restrict__ consts,
    const float* __restrict__ prefix, float* __restrict__ out) {
  const int k = threadIdx.x;
  const int bm = blockIdx.x;
  const float ar = consts[k], ai = consts[Ksz + k];
  float2 w = ((const float2*)prefix)[(size_t)bm * Ksz + k];
  float c = w.x, s = w.y;
  const float* up = U + (size_t)bm * (CHUNK * Ksz) + k;
  float* op = out + (size_t)bm * (CHUNK * 2 * Ksz);
  #pragma unroll 4
  for (int t = 0; t < CHUNK; ++t) {
    float u = up[(size_t)t * Ksz];
    float cn = fmaf(ar, c, fmaf(-ai, s, u));
    s = fmaf(ai, c, ar * s);
    c = cn;
    op[(size_t)t * 2 * Ksz + k] = c;
    op[(size_t)t * 2 * Ksz + Ksz + k] = s;
  }
}

extern "C" void kernel_launch(void* const* d_in, const int* in_sizes, int n_in,
                              void* d_out, int out_size, void* d_ws, size_t ws_size,
                              hipStream_t stream) {
  const float* x    = (const float*)d_in[0];
  const float* srr  = (const float*)d_in[1];
  const float* sim  = (const float*)d_in[2];
  const float* traw = (const float*)d_in[3];
  const float* W    = (const float*)d_in[4];
  const float* bias = (const float*)d_in[5];
  float* out = (float*)d_out;

  // ws layout (floats): consts[4096] | U[16777216] | carry[524288] |
  //   prefix[524288] | WfH[65536] | WfL[65536] | partial_v[8192] | wv[256]
  float* wsf    = (float*)d_ws;
  float* consts = wsf;
  float* U      = wsf + 4096;
  float* carry  = U + (size_t)Msz * Ksz;
  float* prefix = carry + (size_t)2 * Bsz * NCH * Ksz;
  unsigned int* WfH = (unsigned int*)(prefix + (size_t)2 * Bsz * NCH * Ksz);
  unsigned int* WfL = WfH + 65536;
  float* partial_v  = (float*)(WfL + 65536);
  float* wv         = partial_v + 16 * Dsz;

  prep1_kernel<<<16, 512, 0, stream>>>(W, partial_v);
  prep2_kernel<<<64, 512, 0, stream>>>(W, partial_v, wv);
  prep3_kernel<<<1, 256, 0, stream>>>(srr, sim, traw, wv, consts);
  wpack_kernel<<<256, 64, 0, stream>>>(W, consts, WfH, WfL);
  gemm_mfma<<<Msz / 64, 256, 0, stream>>>(x, WfH, WfL, bias, consts, U, carry);
  scan_prefix<<<dim3(Bsz, Ksz / 64), 64, 0, stream>>>(consts, carry, prefix);
  scan_final<<<Bsz * NCH, Ksz, 0, stream>>>(U, consts, prefix, out);
}

// Round 8
// 151.157 us; speedup vs baseline: 1.5590x; 1.5590x over previous
//
#include <hip/hip_runtime.h>

#define Bsz 16
#define Tsz 4096
#define Dsz 512
#define Ksz 256
#define Msz (Bsz * Tsz)      // 65536
#define CHUNK 64
#define NCH (Tsz / CHUNK)    // 64

typedef __attribute__((ext_vector_type(8))) short short8;
typedef __attribute__((ext_vector_type(4))) float f32x4;

// ---------------- threefry2x32 (key = (0, 42)) — matches JAX exactly -------
__device__ __forceinline__ unsigned int rotl32(unsigned int x, int d) {
  return (x << d) | (x >> (32 - d));
}

__device__ void threefry_pair(unsigned int c0, unsigned int c1,
                              unsigned int& o0, unsigned int& o1) {
  const unsigned int k0 = 0u, k1 = 42u;
  const unsigned int k2 = k0 ^ k1 ^ 0x1BD11BDAu;
  unsigned int x0 = c0 + k0;
  unsigned int x1 = c1 + k1;
#define TF_ROUND(r) { x0 += x1; x1 = rotl32(x1, (r)); x1 ^= x0; }
  TF_ROUND(13) TF_ROUND(15) TF_ROUND(26) TF_ROUND(6)
  x0 += k1; x1 += k2 + 1u;
  TF_ROUND(17) TF_ROUND(29) TF_ROUND(16) TF_ROUND(24)
  x0 += k2; x1 += k0 + 2u;
  TF_ROUND(13) TF_ROUND(15) TF_ROUND(26) TF_ROUND(6)
  x0 += k0; x1 += k1 + 3u;
  TF_ROUND(17) TF_ROUND(29) TF_ROUND(16) TF_ROUND(24)
  x0 += k1; x1 += k2 + 4u;
  TF_ROUND(13) TF_ROUND(15) TF_ROUND(26) TF_ROUND(6)
  x0 += k2; x1 += k0 + 5u;
#undef TF_ROUND
  o0 = x0; o1 = x1;
}

// XLA ErfInv32 polynomial (math.cc)
__device__ float erfinv32(float x) {
  float w = -log1pf(-x * x);
  float p;
  if (w < 5.f) {
    w -= 2.5f;
    p = 2.81022636e-08f;
    p = fmaf(p, w, 3.43273939e-07f);
    p = fmaf(p, w, -3.5233877e-06f);
    p = fmaf(p, w, -4.39150654e-06f);
    p = fmaf(p, w, 0.00021858087f);
    p = fmaf(p, w, -0.00125372503f);
    p = fmaf(p, w, -0.00417768164f);
    p = fmaf(p, w, 0.246640727f);
    p = fmaf(p, w, 1.50140941f);
  } else {
    w = sqrtf(w) - 3.f;
    p = -0.000200214257f;
    p = fmaf(p, w, 0.000100950558f);
    p = fmaf(p, w, 0.00134934322f);
    p = fmaf(p, w, -0.00367342844f);
    p = fmaf(p, w, 0.00573950773f);
    p = fmaf(p, w, -0.0076224613f);
    p = fmaf(p, w, 0.00943887047f);
    p = fmaf(p, w, 1.00167406f);
    p = fmaf(p, w, 2.83297682f);
  }
  return p * x;
}

// JAX: bits -> uniform[-0.99999994, 1) -> sqrt(2)*erfinv
__device__ float bits_to_normal(unsigned int bits) {
  unsigned int fb = (bits >> 9) | 0x3f800000u;
  float f = __uint_as_float(fb) - 1.0f;   // [0,1)
  const float lo = -0.99999994f;          // nextafter(-1, 0) in f32
  float u = f * 2.0f + lo;                // hi - lo rounds to exactly 2.0f
  u = fmaxf(lo, u);
  return 1.41421356f * erfinv32(u);
}

__device__ float block_sum_512(float v, float* s_red) {
  #pragma unroll
  for (int o = 32; o > 0; o >>= 1) v += __shfl_down(v, o);
  const int lane = threadIdx.x & 63, wid = threadIdx.x >> 6;
  if (lane == 0) s_red[wid] = v;
  __syncthreads();
  float r = 0.f;
  #pragma unroll
  for (int i = 0; i < 8; ++i) r += s_red[i];
  __syncthreads();
  return r;
}

__device__ __forceinline__ unsigned int bf16rne(float f) {
  unsigned int u = __float_as_uint(f);
  return (u + 0x7FFFu + ((u >> 16) & 1u)) >> 16;
}

// --------- prep1 (16 blocks x 512): partial_v[b][d] = sum_k W[k][d]*u0n[k] --
__global__ __launch_bounds__(512) void prep1_kernel(
    const float* __restrict__ W, float* __restrict__ partial_v) {
  __shared__ float s_u0[Ksz];
  __shared__ float s_red[8];
  const int tid = threadIdx.x;
  if (tid < 128) {
    unsigned int y0, y1;
    threefry_pair((unsigned int)tid, (unsigned int)(tid + 128), y0, y1);
    s_u0[tid] = bits_to_normal(y0);
    s_u0[tid + 128] = bits_to_normal(y1);
  }
  __syncthreads();
  float val = (tid < Ksz) ? s_u0[tid] * s_u0[tid] : 0.f;
  float ss = block_sum_512(val, s_red);
  float inv = 1.f / fmaxf(sqrtf(ss), 1e-7f);

  const int k0 = blockIdx.x * 16;
  float acc = 0.f;
  #pragma unroll
  for (int kk = 0; kk < 16; ++kk)
    acc = fmaf(W[(size_t)(k0 + kk) * Dsz + tid], s_u0[k0 + kk], acc);
  partial_v[blockIdx.x * Dsz + tid] = acc * inv;
}

// --------- prep2 (64 blocks x 512): v = normalize(sum partials); wv rows ---
__global__ __launch_bounds__(512) void prep2_kernel(
    const float* __restrict__ W, const float* __restrict__ partial_v,
    float* __restrict__ wv) {
  __shared__ float s_v[Dsz];
  __shared__ float s_red[8];
  __shared__ float s_p[8];
  const int tid = threadIdx.x;
  float acc = 0.f;
  #pragma unroll
  for (int b = 0; b < 16; ++b) acc += partial_v[b * Dsz + tid];
  float ssv = block_sum_512(acc * acc, s_red);
  float invv = 1.f / fmaxf(sqrtf(ssv), 1e-7f);
  s_v[tid] = acc * invv;
  __syncthreads();

  // 4 rows per block, 128 threads per row
  const int k = blockIdx.x * 4 + (tid >> 7);
  const int sub = tid & 127;
  const float* wr = W + (size_t)k * Dsz;
  float p = 0.f;
  #pragma unroll
  for (int j = sub; j < Dsz; j += 128) p = fmaf(wr[j], s_v[j], p);
  #pragma unroll
  for (int o = 32; o > 0; o >>= 1) p += __shfl_down(p, o);
  const int lane = tid & 63, wid = tid >> 6;
  if (lane == 0) s_p[wid] = p;
  __syncthreads();
  if (tid < 4) wv[blockIdx.x * 4 + tid] = s_p[2 * tid] + s_p[2 * tid + 1];
}

// --------- prep3 (1 block x 256): sigma + all per-k constants --------------
// consts layout (floats): [0]=ar [K]=ai [2K]=A64r [3K]=A64i [4K]=P4r [5K]=P4i
//   [6K]=P8r [7K]=P8i [8K]=P16r [9K]=P16i [10K]=P32r [11K]=P32i [12K]=inv_sigma
__global__ __launch_bounds__(256) void prep3_kernel(
    const float* __restrict__ s_real_raw, const float* __restrict__ s_imag,
    const float* __restrict__ tau_raw, const float* __restrict__ wv,
    float* __restrict__ consts) {
  __shared__ float s_p[4];
  const int tid = threadIdx.x;
  float v = wv[tid];
  float v2 = v * v;
  #pragma unroll
  for (int o = 32; o > 0; o >>= 1) v2 += __shfl_down(v2, o);
  const int lane = tid & 63, wid = tid >> 6;
  if (lane == 0) s_p[wid] = v2;
  __syncthreads();
  float sswv = s_p[0] + s_p[1] + s_p[2] + s_p[3];
  float sigma = sswv / fmaxf(sqrtf(sswv), 1e-7f);
  if (tid == 0) consts[12 * Ksz] = 1.f / sigma;

  float tr = tau_raw[0];
  float tau = fmaxf(tr, 0.f) + log1pf(expf(-fabsf(tr))) + 1e-3f;
  float srr = s_real_raw[tid];
  float sp = fmaxf(srr, 0.f) + log1pf(expf(-fabsf(srr)));
  float alpha0 = (sp + 1e-6f) * tau;
  float omega0 = s_imag[tid] * tau;
  const float dt = 1.f / 4095.f;
  float ad = alpha0 * dt, an = omega0 * dt;
  consts[tid]            = expf(-ad) * cosf(an);
  consts[Ksz + tid]      = expf(-ad) * sinf(an);
  consts[2 * Ksz + tid]  = expf(-ad * 64.f) * cosf(an * 64.f);
  consts[3 * Ksz + tid]  = expf(-ad * 64.f) * sinf(an * 64.f);
  consts[4 * Ksz + tid]  = expf(-ad * 4.f) * cosf(an * 4.f);
  consts[5 * Ksz + tid]  = expf(-ad * 4.f) * sinf(an * 4.f);
  consts[6 * Ksz + tid]  = expf(-ad * 8.f) * cosf(an * 8.f);
  consts[7 * Ksz + tid]  = expf(-ad * 8.f) * sinf(an * 8.f);
  consts[8 * Ksz + tid]  = expf(-ad * 16.f) * cosf(an * 16.f);
  consts[9 * Ksz + tid]  = expf(-ad * 16.f) * sinf(an * 16.f);
  consts[10 * Ksz + tid] = expf(-ad * 32.f) * cosf(an * 32.f);
  consts[11 * Ksz + tid] = expf(-ad * 32.f) * sinf(an * 32.f);
}

// --------- wpack: W/sigma -> bf16 h/l in MFMA B-fragment order -------------
__global__ __launch_bounds__(64) void wpack_kernel(
    const float* __restrict__ W, const float* __restrict__ consts,
    unsigned int* __restrict__ WfH, unsigned int* __restrict__ WfL) {
  const int kb = blockIdx.x >> 4;
  const int nb = blockIdx.x & 15;
  const int lane = threadIdx.x;
  const int lr = lane & 15, lg = lane >> 4;
  const float inv_sigma = consts[12 * Ksz];
  const float* src = W + (size_t)(nb * 16 + lr) * Dsz + kb * 32 + lg * 8;
  float v[8];
  *(float4*)&v[0] = *(const float4*)src;
  *(float4*)&v[4] = *(const float4*)(src + 4);
  unsigned int hh[4], ll[4];
  #pragma unroll
  for (int i = 0; i < 4; ++i) {
    float v0 = v[2 * i] * inv_sigma, v1 = v[2 * i + 1] * inv_sigma;
    unsigned int u0 = __float_as_uint(v0);
    unsigned int u1 = __float_as_uint(v1);
    hh[i] = (u0 >> 16) | (u1 & 0xFFFF0000u);
    float r0 = v0 - __uint_as_float(u0 & 0xFFFF0000u);
    float r1 = v1 - __uint_as_float(u1 & 0xFFFF0000u);
    ll[i] = bf16rne(r0) | (bf16rne(r1) << 16);
  }
  const size_t off = (size_t)blockIdx.x * 256 + lane * 4;   // in uints
  *(int4*)(WfH + off) = *(int4*)hh;
  *(int4*)(WfL + off) = *(int4*)ll;
}

// --------- MFMA GEMM + fused chunk-scan carry ------------------------------
// BM=64 (= one scan chunk), BN=256, BK=32. 512 threads = 8 waves, 2m x 4n:
// wave owns 32 rows x 64 cols -> acc[2][4] (32 regs), frags [2] (16), B
// single-buffer (32). ~130 regs -> 3+ waves/SIMD (round-5 had 2, lockstep).
// Schedule = round-5's proven single-barrier LDS dbuf; TLP (cross-block wave
// interleave) hides the serial chain instead of in-wave ILP.
// Epilogue: U store + per-half carry partials combined via LDS scratch:
//   carry = P32 * S_low + S_high.
__global__ __launch_bounds__(512, 3) void gemm_mfma(
    const float* __restrict__ X, const unsigned int* __restrict__ WfH,
    const unsigned int* __restrict__ WfL, const float* __restrict__ bias,
    const float* __restrict__ consts, float* __restrict__ U,
    float* __restrict__ carry) {
  __shared__ unsigned int ldsA[2][2048];   // 2 x 8KB: 64 rows x [64B h|64B l]

  const int tid = threadIdx.x;
  const size_t m0 = (size_t)blockIdx.x * 64;

  // A staging: thread -> (row sr = tid>>3, k-chunk sc = (tid&7)*4 floats)
  const int sr = tid >> 3;              // 0..63
  const int sc = (tid & 7) * 4;         // 0,4,...,28
  const float* gx = X + (m0 + sr) * Dsz + sc;
  const int swz = (sr & 7) << 4;
  const int aoff_h = sr * 128 + ((sc * 2) ^ swz);
  const int aoff_l = sr * 128 + ((64 + sc * 2) ^ swz);

  const int lane = tid & 63;
  const int wid = tid >> 6;             // 0..7
  const int wm = wid >> 2;              // 0..1 -> rows wm*32
  const int wn2 = wid & 3;              // 0..3 -> cols wn2*64
  const int lr = lane & 15;
  const int lg = lane >> 4;

  float xaA[4], xaB[4];
  #define LOAD_A(dst, kb) do {                                               \
    *(float4*)&dst[0] = *(const float4*)(gx + (kb) * 32);                    \
  } while (0)

  const char* const wfh = (const char*)WfH + (size_t)wn2 * 4096 + lane * 16;
  const char* const wfl = (const char*)WfL + (size_t)wn2 * 4096 + lane * 16;

  short8 bh[4], bl[4];                  // single-buffer B (L2-hot)
  #define LOAD_B(kb) do {                                                    \
    const size_t tb = (size_t)(kb) * 16384;                                  \
    _Pragma("unroll")                                                        \
    for (int f = 0; f < 4; ++f) {                                            \
      bh[f] = *(const short8*)(wfh + tb + (size_t)f * 1024);                 \
      bl[f] = *(const short8*)(wfl + tb + (size_t)f * 1024);                 \
    }                                                                        \
  } while (0)

  #define CONVERT_STORE(xa, buf) do {                                        \
    char* const Ab_ = (char*)ldsA[(buf)];                                    \
    unsigned int hh[2], llw[2];                                              \
    _Pragma("unroll")                                                        \
    for (int i = 0; i < 2; ++i) {                                            \
      float v0 = xa[2 * i], v1 = xa[2 * i + 1];                              \
      unsigned int u0 = __float_as_uint(v0);                                 \
      unsigned int u1 = __float_as_uint(v1);                                 \
      hh[i] = (u0 >> 16) | (u1 & 0xFFFF0000u);                               \
      float r0 = v0 - __uint_as_float(u0 & 0xFFFF0000u);                     \
      float r1 = v1 - __uint_as_float(u1 & 0xFFFF0000u);                     \
      llw[i] = bf16rne(r0) | (bf16rne(r1) << 16);                            \
    }                                                                        \
    *(int2*)(Ab_ + aoff_h) = *(int2*)hh;                                     \
    *(int2*)(Ab_ + aoff_l) = *(int2*)llw;                                    \
  } while (0)

  short8 ah[2], al[2];
  #define DS_READ(buf) do {                                                  \
    const char* const Ab_ = (const char*)ldsA[(buf)];                        \
    _Pragma("unroll")                                                        \
    for (int f = 0; f < 2; ++f) {                                            \
      const int r = wm * 32 + f * 16 + lr;                                   \
      const int sz = (r & 7) << 4;                                           \
      ah[f] = *(const short8*)(Ab_ + r * 128 + ((lg * 16) ^ sz));            \
      al[f] = *(const short8*)(Ab_ + r * 128 + ((64 + lg * 16) ^ sz));       \
    }                                                                        \
  } while (0)

  f32x4 acc[2][4];
  #pragma unroll
  for (int i = 0; i < 2; ++i)
    #pragma unroll
    for (int j = 0; j < 4; ++j) acc[i][j] = (f32x4)(0.f);

  #define MFMA24() do {                                                      \
    _Pragma("unroll")                                                        \
    for (int mf = 0; mf < 2; ++mf)                                           \
      _Pragma("unroll")                                                      \
      for (int nf = 0; nf < 4; ++nf)                                         \
        acc[mf][nf] = __builtin_amdgcn_mfma_f32_16x16x32_bf16(               \
            ah[mf], bh[nf], acc[mf][nf], 0, 0, 0);                           \
    _Pragma("unroll")                                                        \
    for (int mf = 0; mf < 2; ++mf)                                           \
      _Pragma("unroll")                                                      \
      for (int nf = 0; nf < 4; ++nf)                                         \
        acc[mf][nf] = __builtin_amdgcn_mfma_f32_16x16x32_bf16(               \
            ah[mf], bl[nf], acc[mf][nf], 0, 0, 0);                           \
    _Pragma("unroll")                                                        \
    for (int mf = 0; mf < 2; ++mf)                                           \
      _Pragma("unroll")                                                      \
      for (int nf = 0; nf < 4; ++nf)                                         \
        acc[mf][nf] = __builtin_amdgcn_mfma_f32_16x16x32_bf16(               \
            al[mf], bh[nf], acc[mf][nf], 0, 0, 0);                           \
  } while (0)

  #define SYNC() do {                                                        \
    asm volatile("s_waitcnt lgkmcnt(0)" ::: "memory");                       \
    __builtin_amdgcn_s_barrier();                                            \
    __builtin_amdgcn_sched_barrier(0);                                       \
  } while (0)

  // ---- prologue ----
  LOAD_A(xaA, 0);
  LOAD_A(xaB, 1);
  CONVERT_STORE(xaA, 0);        // tile 0 -> buf0
  LOAD_A(xaA, 2);
  SYNC();
  // invariant: even kb -> xaB holds tile kb+1; odd kb -> xaA holds tile kb+1

  #define BODY(kb, xa) do {                                                  \
    DS_READ((kb) & 1);                   /* tile kb fragments */             \
    LOAD_B(kb);                          /* B for this tile (L2) */          \
    if ((kb) + 1 < 16) CONVERT_STORE(xa, ((kb) + 1) & 1);                    \
    if ((kb) + 3 < 16) LOAD_A(xa, (kb) + 3);                                 \
    MFMA24();                                                                \
    SYNC();                                                                  \
  } while (0)

  for (int kb = 0; kb < 16; kb += 2) {
    BODY(kb,     xaB);
    BODY(kb + 1, xaA);
  }
  #undef BODY
  #undef SYNC
  #undef MFMA24
  #undef DS_READ
  #undef CONVERT_STORE
  #undef LOAD_B
  #undef LOAD_A

  // ---- epilogue: U store + fused chunk carry (two 32-halves) ----
  // local tt = mf*16 + lg*4 + j in [0,32); weight a^{31-tt} =
  //   P16^{1-mf} * P4^{3-lg} * a^{3-j}; carry = P32*S(wm=0) + S(wm=1).
  float2* scratch = (float2*)ldsA;      // 512 float2 = 4KB, loop LDS done
  #pragma unroll
  for (int nf = 0; nf < 4; ++nf) {
    const int n = wn2 * 64 + nf * 16 + lr;
    const float bv = bias[n];
    const float ar_ = consts[n],           ai_ = consts[Ksz + n];
    const float p4r = consts[4 * Ksz + n], p4i = consts[5 * Ksz + n];
    const float p8r = consts[6 * Ksz + n], p8i = consts[7 * Ksz + n];
    const float p16r = consts[8 * Ksz + n], p16i = consts[9 * Ksz + n];
    const int e = 3 - lg;
    const float b1r = (e & 1) ? p4r : 1.f, b1i = (e & 1) ? p4i : 0.f;
    const float b2r = (e & 2) ? p8r : 1.f, b2i = (e & 2) ? p8i : 0.f;
    float wr = b1r * b2r - b1i * b2i;
    float wi = b1r * b2i + b1i * b2r;
    float Sr = 0.f, Si = 0.f;
    #pragma unroll
    for (int mf = 1; mf >= 0; --mf) {
      float vr = wr, vi = wi;
      #pragma unroll
      for (int j = 3; j >= 0; --j) {
        const float u = acc[mf][nf][j] + bv;
        U[(m0 + wm * 32 + mf * 16 + lg * 4 + j) * Ksz + n] = u;
        Sr = fmaf(u, vr, Sr);
        Si = fmaf(u, vi, Si);
        if (j) {
          float t_ = vr * ar_ - vi * ai_;
          vi = vr * ai_ + vi * ar_;
          vr = t_;
        }
      }
      if (mf) {
        float t_ = wr * p16r - wi * p16i;
        wi = wr * p16i + wi * p16r;
        wr = t_;
      }
    }
    Sr += __shfl_xor(Sr, 16); Si += __shfl_xor(Si, 16);
    Sr += __shfl_xor(Sr, 32); Si += __shfl_xor(Si, 32);
    if (lg == 0) {
      float pr = Sr, pi = Si;
      if (wm == 0) {
        const float p32r = consts[10 * Ksz + n], p32i = consts[11 * Ksz + n];
        pr = Sr * p32r - Si * p32i;
        pi = Sr * p32i + Si * p32r;
      }
      scratch[wm * 256 + n] = make_float2(pr, pi);
    }
  }
  __syncthreads();
  if (wm == 0 && lg == 0) {
    #pragma unroll
    for (int nf = 0; nf < 4; ++nf) {
      const int n = wn2 * 64 + nf * 16 + lr;
      float2 a0 = scratch[n], a1 = scratch[256 + n];
      ((float2*)carry)[(size_t)blockIdx.x * Ksz + n] =
          make_float2(a0.x + a1.x, a0.y + a1.y);
    }
  }
}

// --------- scan pass 2: exclusive prefix over chunks (A = a^64) ------------
__global__ __launch_bounds__(64) void scan_prefix(
    const float* __restrict__ consts, const float* __restrict__ carry,
    float* __restrict__ prefix) {
  const int k = blockIdx.y * 64 + threadIdx.x;
  const int b = blockIdx.x;
  const float Ar = consts[2 * Ksz + k], Ai = consts[3 * Ksz + k];
  const float2* cp = (const float2*)carry;
  float2* pp = (float2*)prefix;
  float c = 0.f, s = 0.f;
  for (int m = 0; m < NCH; ++m) {
    const size_t idx = (size_t)(b * NCH + m) * Ksz + k;
    pp[idx] = make_float2(c, s);
    float2 L = cp[idx];
    float cn = fmaf(Ar, c, fmaf(-Ai, s, L.x));
    float sn = fmaf(Ai, c, fmaf(Ar, s, L.y));
    c = cn; s = sn;
  }
}

// --------- scan pass 3: rescan chunk from true carry, write output ---------
__global__ __launch_bounds__(256) void scan_final(
    const float* __restrict__ U, const float* __restrict__ consts,
    const float* __restrict__ prefix, float* __restrict__ out) {
  const int k = threadIdx.x;
  const int bm = blockIdx.x;
  const float ar = consts[k], ai = consts[Ksz + k];
  float2 w = ((const float2*)prefix)[(size_t)bm * Ksz + k];
  float c = w.x, s = w.y;
  const float* up = U + (size_t)bm * (CHUNK * Ksz) + k;
  float* op = out + (size_t)bm * (CHUNK * 2 * Ksz);
  #pragma unroll 4
  for (int t = 0; t < CHUNK; ++t) {
    float u = up[(size_t)t * Ksz];
    float cn = fmaf(ar, c, fmaf(-ai, s, u));
    s = fmaf(ai, c, ar * s);
    c = cn;
    op[(size_t)t * 2 * Ksz + k] = c;
    op[(size_t)t * 2 * Ksz + Ksz + k] = s;
  }
}

extern "C" void kernel_launch(void* const* d_in, const int* in_sizes, int n_in,
                              void* d_out, int out_size, void* d_ws, size_t ws_size,
                              hipStream_t stream) {
  const float* x    = (const float*)d_in[0];
  const float* srr  = (const float*)d_in[1];
  const float* sim  = (const float*)d_in[2];
  const float* traw = (const float*)d_in[3];
  const float* W    = (const float*)d_in[4];
  const float* bias = (const float*)d_in[5];
  float* out = (float*)d_out;

  // ws layout (floats): consts[4096] | U[16777216] | carry[524288] |
  //   prefix[524288] | WfH[65536] | WfL[65536] | partial_v[8192] | wv[256]
  float* wsf    = (float*)d_ws;
  float* consts = wsf;
  float* U      = wsf + 4096;
  float* carry  = U + (size_t)Msz * Ksz;
  float* prefix = carry + (size_t)2 * Bsz * NCH * Ksz;
  unsigned int* WfH = (unsigned int*)(prefix + (size_t)2 * Bsz * NCH * Ksz);
  unsigned int* WfL = WfH + 65536;
  float* partial_v  = (float*)(WfL + 65536);
  float* wv         = partial_v + 16 * Dsz;

  prep1_kernel<<<16, 512, 0, stream>>>(W, partial_v);
  prep2_kernel<<<64, 512, 0, stream>>>(W, partial_v, wv);
  prep3_kernel<<<1, 256, 0, stream>>>(srr, sim, traw, wv, consts);
  wpack_kernel<<<256, 64, 0, stream>>>(W, consts, WfH, WfL);
  gemm_mfma<<<Msz / 64, 512, 0, stream>>>(x, WfH, WfL, bias, consts, U, carry);
  scan_prefix<<<dim3(Bsz, Ksz / 64), 64, 0, stream>>>(consts, carry, prefix);
  scan_final<<<Bsz * NCH, Ksz, 0, stream>>>(U, consts, prefix, out);
}

// Round 9
// 146.607 us; speedup vs baseline: 1.6074x; 1.0310x over previous
//
#include <hip/hip_runtime.h>

#define Bsz 16
#define Tsz 4096
#define Dsz 512
#define Ksz 256
#define Msz (Bsz * Tsz)      // 65536
#define CHUNK 64
#define NCH (Tsz / CHUNK)    // 64

typedef __attribute__((ext_vector_type(8))) short short8;
typedef __attribute__((ext_vector_type(4))) float f32x4;
typedef __attribute__((ext_vector_type(4))) unsigned int u32x4;

// ---------------- threefry2x32 (key = (0, 42)) — matches JAX exactly -------
__device__ __forceinline__ unsigned int rotl32(unsigned int x, int d) {
  return (x << d) | (x >> (32 - d));
}

__device__ void threefry_pair(unsigned int c0, unsigned int c1,
                              unsigned int& o0, unsigned int& o1) {
  const unsigned int k0 = 0u, k1 = 42u;
  const unsigned int k2 = k0 ^ k1 ^ 0x1BD11BDAu;
  unsigned int x0 = c0 + k0;
  unsigned int x1 = c1 + k1;
#define TF_ROUND(r) { x0 += x1; x1 = rotl32(x1, (r)); x1 ^= x0; }
  TF_ROUND(13) TF_ROUND(15) TF_ROUND(26) TF_ROUND(6)
  x0 += k1; x1 += k2 + 1u;
  TF_ROUND(17) TF_ROUND(29) TF_ROUND(16) TF_ROUND(24)
  x0 += k2; x1 += k0 + 2u;
  TF_ROUND(13) TF_ROUND(15) TF_ROUND(26) TF_ROUND(6)
  x0 += k0; x1 += k1 + 3u;
  TF_ROUND(17) TF_ROUND(29) TF_ROUND(16) TF_ROUND(24)
  x0 += k1; x1 += k2 + 4u;
  TF_ROUND(13) TF_ROUND(15) TF_ROUND(26) TF_ROUND(6)
  x0 += k2; x1 += k0 + 5u;
#undef TF_ROUND
  o0 = x0; o1 = x1;
}

// XLA ErfInv32 polynomial (math.cc)
__device__ float erfinv32(float x) {
  float w = -log1pf(-x * x);
  float p;
  if (w < 5.f) {
    w -= 2.5f;
    p = 2.81022636e-08f;
    p = fmaf(p, w, 3.43273939e-07f);
    p = fmaf(p, w, -3.5233877e-06f);
    p = fmaf(p, w, -4.39150654e-06f);
    p = fmaf(p, w, 0.00021858087f);
    p = fmaf(p, w, -0.00125372503f);
    p = fmaf(p, w, -0.00417768164f);
    p = fmaf(p, w, 0.246640727f);
    p = fmaf(p, w, 1.50140941f);
  } else {
    w = sqrtf(w) - 3.f;
    p = -0.000200214257f;
    p = fmaf(p, w, 0.000100950558f);
    p = fmaf(p, w, 0.00134934322f);
    p = fmaf(p, w, -0.00367342844f);
    p = fmaf(p, w, 0.00573950773f);
    p = fmaf(p, w, -0.0076224613f);
    p = fmaf(p, w, 0.00943887047f);
    p = fmaf(p, w, 1.00167406f);
    p = fmaf(p, w, 2.83297682f);
  }
  return p * x;
}

// JAX: bits -> uniform[-0.99999994, 1) -> sqrt(2)*erfinv
__device__ float bits_to_normal(unsigned int bits) {
  unsigned int fb = (bits >> 9) | 0x3f800000u;
  float f = __uint_as_float(fb) - 1.0f;   // [0,1)
  const float lo = -0.99999994f;          // nextafter(-1, 0) in f32
  float u = f * 2.0f + lo;                // hi - lo rounds to exactly 2.0f
  u = fmaxf(lo, u);
  return 1.41421356f * erfinv32(u);
}

__device__ float block_sum_512(float v, float* s_red) {
  #pragma unroll
  for (int o = 32; o > 0; o >>= 1) v += __shfl_down(v, o);
  const int lane = threadIdx.x & 63, wid = threadIdx.x >> 6;
  if (lane == 0) s_red[wid] = v;
  __syncthreads();
  float r = 0.f;
  #pragma unroll
  for (int i = 0; i < 8; ++i) r += s_red[i];
  __syncthreads();
  return r;
}

__device__ __forceinline__ unsigned int bf16rne(float f) {
  unsigned int u = __float_as_uint(f);
  return (u + 0x7FFFu + ((u >> 16) & 1u)) >> 16;
}

__device__ __forceinline__ void gld16(const float* g, float* l) {
  using gp = const __attribute__((address_space(1))) unsigned int*;
  using lp = __attribute__((address_space(3))) unsigned int*;
  __builtin_amdgcn_global_load_lds((gp)(const void*)g, (lp)(void*)l, 16, 0, 0);
}

// --------- prep1 (16 blocks x 512): partial_v[b][d] = sum_k W[k][d]*u0n[k] --
__global__ __launch_bounds__(512) void prep1_kernel(
    const float* __restrict__ W, float* __restrict__ partial_v) {
  __shared__ float s_u0[Ksz];
  __shared__ float s_red[8];
  const int tid = threadIdx.x;
  if (tid < 128) {
    unsigned int y0, y1;
    threefry_pair((unsigned int)tid, (unsigned int)(tid + 128), y0, y1);
    s_u0[tid] = bits_to_normal(y0);
    s_u0[tid + 128] = bits_to_normal(y1);
  }
  __syncthreads();
  float val = (tid < Ksz) ? s_u0[tid] * s_u0[tid] : 0.f;
  float ss = block_sum_512(val, s_red);
  float inv = 1.f / fmaxf(sqrtf(ss), 1e-7f);

  const int k0 = blockIdx.x * 16;
  float acc = 0.f;
  #pragma unroll
  for (int kk = 0; kk < 16; ++kk)
    acc = fmaf(W[(size_t)(k0 + kk) * Dsz + tid], s_u0[k0 + kk], acc);
  partial_v[blockIdx.x * Dsz + tid] = acc * inv;
}

// --------- prep2 (64 blocks x 512): v = normalize(sum partials); wv rows ---
__global__ __launch_bounds__(512) void prep2_kernel(
    const float* __restrict__ W, const float* __restrict__ partial_v,
    float* __restrict__ wv) {
  __shared__ float s_v[Dsz];
  __shared__ float s_red[8];
  __shared__ float s_p[8];
  const int tid = threadIdx.x;
  float acc = 0.f;
  #pragma unroll
  for (int b = 0; b < 16; ++b) acc += partial_v[b * Dsz + tid];
  float ssv = block_sum_512(acc * acc, s_red);
  float invv = 1.f / fmaxf(sqrtf(ssv), 1e-7f);
  s_v[tid] = acc * invv;
  __syncthreads();

  const int k = blockIdx.x * 4 + (tid >> 7);
  const int sub = tid & 127;
  const float* wr = W + (size_t)k * Dsz;
  float p = 0.f;
  #pragma unroll
  for (int j = sub; j < Dsz; j += 128) p = fmaf(wr[j], s_v[j], p);
  #pragma unroll
  for (int o = 32; o > 0; o >>= 1) p += __shfl_down(p, o);
  const int lane = tid & 63, wid = tid >> 6;
  if (lane == 0) s_p[wid] = p;
  __syncthreads();
  if (tid < 4) wv[blockIdx.x * 4 + tid] = s_p[2 * tid] + s_p[2 * tid + 1];
}

// --------- prep3 (1 block x 256): sigma + all per-k constants --------------
// consts layout (floats): [0]=ar [K]=ai [2K]=A64r [3K]=A64i [4K]=P4r [5K]=P4i
//   [6K]=P8r [7K]=P8i [8K]=P16r [9K]=P16i [10K]=P32r [11K]=P32i [12K]=inv_sigma
__global__ __launch_bounds__(256) void prep3_kernel(
    const float* __restrict__ s_real_raw, const float* __restrict__ s_imag,
    const float* __restrict__ tau_raw, const float* __restrict__ wv,
    float* __restrict__ consts) {
  __shared__ float s_p[4];
  const int tid = threadIdx.x;
  float v = wv[tid];
  float v2 = v * v;
  #pragma unroll
  for (int o = 32; o > 0; o >>= 1) v2 += __shfl_down(v2, o);
  const int lane = tid & 63, wid = tid >> 6;
  if (lane == 0) s_p[wid] = v2;
  __syncthreads();
  float sswv = s_p[0] + s_p[1] + s_p[2] + s_p[3];
  float sigma = sswv / fmaxf(sqrtf(sswv), 1e-7f);
  if (tid == 0) consts[12 * Ksz] = 1.f / sigma;

  float tr = tau_raw[0];
  float tau = fmaxf(tr, 0.f) + log1pf(expf(-fabsf(tr))) + 1e-3f;
  float srr = s_real_raw[tid];
  float sp = fmaxf(srr, 0.f) + log1pf(expf(-fabsf(srr)));
  float alpha0 = (sp + 1e-6f) * tau;
  float omega0 = s_imag[tid] * tau;
  const float dt = 1.f / 4095.f;
  float ad = alpha0 * dt, an = omega0 * dt;
  consts[tid]            = expf(-ad) * cosf(an);
  consts[Ksz + tid]      = expf(-ad) * sinf(an);
  consts[2 * Ksz + tid]  = expf(-ad * 64.f) * cosf(an * 64.f);
  consts[3 * Ksz + tid]  = expf(-ad * 64.f) * sinf(an * 64.f);
  consts[4 * Ksz + tid]  = expf(-ad * 4.f) * cosf(an * 4.f);
  consts[5 * Ksz + tid]  = expf(-ad * 4.f) * sinf(an * 4.f);
  consts[6 * Ksz + tid]  = expf(-ad * 8.f) * cosf(an * 8.f);
  consts[7 * Ksz + tid]  = expf(-ad * 8.f) * sinf(an * 8.f);
  consts[8 * Ksz + tid]  = expf(-ad * 16.f) * cosf(an * 16.f);
  consts[9 * Ksz + tid]  = expf(-ad * 16.f) * sinf(an * 16.f);
  consts[10 * Ksz + tid] = expf(-ad * 32.f) * cosf(an * 32.f);
  consts[11 * Ksz + tid] = expf(-ad * 32.f) * sinf(an * 32.f);
}

// --------- wpack: W/sigma -> bf16 h/l in MFMA B-fragment order -------------
__global__ __launch_bounds__(64) void wpack_kernel(
    const float* __restrict__ W, const float* __restrict__ consts,
    unsigned int* __restrict__ WfH, unsigned int* __restrict__ WfL) {
  const int kb = blockIdx.x >> 4;
  const int nb = blockIdx.x & 15;
  const int lane = threadIdx.x;
  const int lr = lane & 15, lg = lane >> 4;
  const float inv_sigma = consts[12 * Ksz];
  const float* src = W + (size_t)(nb * 16 + lr) * Dsz + kb * 32 + lg * 8;
  float v[8];
  *(float4*)&v[0] = *(const float4*)src;
  *(float4*)&v[4] = *(const float4*)(src + 4);
  unsigned int hh[4], ll[4];
  #pragma unroll
  for (int i = 0; i < 4; ++i) {
    float v0 = v[2 * i] * inv_sigma, v1 = v[2 * i + 1] * inv_sigma;
    unsigned int u0 = __float_as_uint(v0);
    unsigned int u1 = __float_as_uint(v1);
    hh[i] = (u0 >> 16) | (u1 & 0xFFFF0000u);
    float r0 = v0 - __uint_as_float(u0 & 0xFFFF0000u);
    float r1 = v1 - __uint_as_float(u1 & 0xFFFF0000u);
    ll[i] = bf16rne(r0) | (bf16rne(r1) << 16);
  }
  const size_t off = (size_t)blockIdx.x * 256 + lane * 4;   // in uints
  *(int4*)(WfH + off) = *(int4*)hh;
  *(int4*)(WfL + off) = *(int4*)ll;
}

// --------- MFMA GEMM + fused chunk-scan carry ------------------------------
// BM=64 (= one scan chunk), BN=256, BK=32, 256 thr = 4 waves (2m x 2n).
// m97-pattern staging: raw f32 A tiles via global_load_lds into a 4-slot LDS
// ring (source-address XOR swizzle, 16B-block c^=(r&7)); counted vmcnt keeps
// 2 tiles in flight across every barrier; consume-side f32->bf16 h/l split
// (bit-identical math to rounds 1-8). One raw s_barrier per phase, no lgkm
// drain, no ds_write. Epilogue: round-8's validated carry (P32 combine).
__global__ __launch_bounds__(256, 2) void gemm_mfma(
    const float* __restrict__ X, const unsigned int* __restrict__ WfH,
    const unsigned int* __restrict__ WfL, const float* __restrict__ bias,
    const float* __restrict__ consts, float* __restrict__ U,
    float* __restrict__ carry) {
  __shared__ float ldsA[4][2048];   // 4 slots x 8KB (64 rows x 32 f32)

  const int tid = threadIdx.x;
  const size_t m0 = (size_t)blockIdx.x * 64;
  const int lane = tid & 63;
  const int wid = tid >> 6;        // 0..3
  const int wm = wid >> 1;         // 0..1 -> rows wm*32
  const int wn = wid & 1;          // 0..1 -> cols wn*128
  const int lr = lane & 15;
  const int lg = lane >> 4;

  // staging source (per lane): LDS block b = wid*128 + lane (+64 for call 2)
  // holds global (r = b>>3, c = (b&7) ^ (r&7)).
  const int arow = wid * 16 + (lane >> 3);
  const int acol = (lane & 7) ^ (lane >> 3);
  const float* gsrc0 = X + (m0 + arow) * Dsz + acol * 4;
  const float* gsrc1 = gsrc0 + 8 * Dsz;

  #define STAGE(P) do {                                                      \
    float* l0 = &ldsA[(P) & 3][0] + wid * 512;                               \
    gld16(gsrc0 + (P) * 32, l0);                                             \
    gld16(gsrc1 + (P) * 32, l0 + 256);                                       \
  } while (0)

  // fragment read offsets (floats within a slot), frag f = 0,1
  int offA[2], offB[2];
  #pragma unroll
  for (int f = 0; f < 2; ++f) {
    const int r = wm * 32 + f * 16 + lr;
    const int s = r & 7;
    offA[f] = (r * 8 + ((lg * 2) ^ s)) * 4;
    offB[f] = (r * 8 + ((lg * 2 + 1) ^ s)) * 4;
  }

  const char* const wfhp = (const char*)WfH + lane * 16;
  const char* const wflp = (const char*)WfL + lane * 16;

  short8 bh1[4], bl1[4], bh2[4], bl2[4];
  #define LOADB(P, H, bh_, bl_) do {                                         \
    const size_t base = ((size_t)(P) * 16 + wn * 8 + (H) * 4) * 1024;        \
    _Pragma("unroll")                                                        \
    for (int q = 0; q < 4; ++q) {                                            \
      bh_[q] = *(const short8*)(wfhp + base + q * 1024);                     \
      bl_[q] = *(const short8*)(wflp + base + q * 1024);                     \
    }                                                                        \
  } while (0)

  short8 ah[2], al[2];
  #define READCVT(P) do {                                                    \
    const float* Ab = &ldsA[(P) & 3][0];                                     \
    _Pragma("unroll")                                                        \
    for (int f = 0; f < 2; ++f) {                                            \
      float4 va = *(const float4*)(Ab + offA[f]);                            \
      float4 vb = *(const float4*)(Ab + offB[f]);                            \
      float v[8] = {va.x, va.y, va.z, va.w, vb.x, vb.y, vb.z, vb.w};         \
      unsigned int hh[4], llw[4];                                            \
      _Pragma("unroll")                                                      \
      for (int i = 0; i < 4; ++i) {                                          \
        float v0 = v[2 * i], v1 = v[2 * i + 1];                              \
        unsigned int u0 = __float_as_uint(v0);                               \
        unsigned int u1 = __float_as_uint(v1);                               \
        hh[i] = (u0 >> 16) | (u1 & 0xFFFF0000u);                             \
        float r0 = v0 - __uint_as_float(u0 & 0xFFFF0000u);                   \
        float r1 = v1 - __uint_as_float(u1 & 0xFFFF0000u);                   \
        llw[i] = bf16rne(r0) | (bf16rne(r1) << 16);                          \
      }                                                                      \
      u32x4 th = {hh[0], hh[1], hh[2], hh[3]};                               \
      u32x4 tl = {llw[0], llw[1], llw[2], llw[3]};                           \
      ah[f] = __builtin_bit_cast(short8, th);                                \
      al[f] = __builtin_bit_cast(short8, tl);                                \
    }                                                                        \
  } while (0)

  f32x4 acc[2][8];
  #pragma unroll
  for (int i = 0; i < 2; ++i)
    #pragma unroll
    for (int j = 0; j < 8; ++j) acc[i][j] = (f32x4)(0.f);

  // per-acc order hh -> hl -> lh (bit-identical to prior rounds)
  #define MFMA_G(G, bh_, bl_) do {                                           \
    _Pragma("unroll")                                                        \
    for (int mf = 0; mf < 2; ++mf)                                           \
      _Pragma("unroll")                                                      \
      for (int q = 0; q < 4; ++q)                                            \
        acc[mf][(G) * 4 + q] = __builtin_amdgcn_mfma_f32_16x16x32_bf16(      \
            ah[mf], bh_[q], acc[mf][(G) * 4 + q], 0, 0, 0);                  \
    _Pragma("unroll")                                                        \
    for (int mf = 0; mf < 2; ++mf)                                           \
      _Pragma("unroll")                                                      \
      for (int q = 0; q < 4; ++q)                                            \
        acc[mf][(G) * 4 + q] = __builtin_amdgcn_mfma_f32_16x16x32_bf16(      \
            ah[mf], bl_[q], acc[mf][(G) * 4 + q], 0, 0, 0);                  \
    _Pragma("unroll")                                                        \
    for (int mf = 0; mf < 2; ++mf)                                           \
      _Pragma("unroll")                                                      \
      for (int q = 0; q < 4; ++q)                                            \
        acc[mf][(G) * 4 + q] = __builtin_amdgcn_mfma_f32_16x16x32_bf16(      \
            al[mf], bh_[q], acc[mf][(G) * 4 + q], 0, 0, 0);                  \
  } while (0)

  #define SB() __builtin_amdgcn_sched_barrier(0)

  // Phase P: issue B halves + stage(P+2); barrier; read+convert tile P;
  // counted waits keep stage pipeline (2 tiles) in flight.
  #define PHASE(P, VM1, VM2) do {                                            \
    LOADB(P, 0, bh1, bl1);                                                   \
    LOADB(P, 1, bh2, bl2);                                                   \
    if ((P) + 2 < 16) STAGE((P) + 2);                                        \
    __builtin_amdgcn_s_barrier(); SB();                                      \
    READCVT(P);                                                              \
    asm volatile("s_waitcnt vmcnt(" #VM1 ")" ::: "memory"); SB();            \
    MFMA_G(0, bh1, bl1);                                                     \
    asm volatile("s_waitcnt vmcnt(" #VM2 ")" ::: "memory"); SB();            \
    MFMA_G(1, bh2, bl2);                                                     \
  } while (0)

  // prologue: stage tiles 0,1; ensure own stage(0) landed before barrier(0)
  STAGE(0);
  STAGE(1);
  asm volatile("s_waitcnt vmcnt(2)" ::: "memory");

  PHASE(0, 10, 2);  PHASE(1, 10, 2);  PHASE(2, 10, 2);  PHASE(3, 10, 2);
  PHASE(4, 10, 2);  PHASE(5, 10, 2);  PHASE(6, 10, 2);  PHASE(7, 10, 2);
  PHASE(8, 10, 2);  PHASE(9, 10, 2);  PHASE(10, 10, 2); PHASE(11, 10, 2);
  PHASE(12, 10, 2); PHASE(13, 10, 2); PHASE(14, 8, 0);  PHASE(15, 8, 0);

  #undef PHASE
  #undef SB
  #undef MFMA_G
  #undef READCVT
  #undef LOADB
  #undef STAGE

  // ---- epilogue: U store + fused chunk carry (two 32-halves) ----
  // local tt = mf*16 + lg*4 + j in [0,32); weight a^{31-tt} =
  //   P16^{1-mf} * P4^{3-lg} * a^{3-j}; carry = P32*S(wm=0) + S(wm=1).
  float2* scratch = (float2*)&ldsA[0][0];   // 4KB, loop LDS done
  #pragma unroll
  for (int f = 0; f < 8; ++f) {
    const int n = wn * 128 + f * 16 + lr;
    const float bv = bias[n];
    const float ar_ = consts[n],           ai_ = consts[Ksz + n];
    const float p4r = consts[4 * Ksz + n], p4i = consts[5 * Ksz + n];
    const float p8r = consts[6 * Ksz + n], p8i = consts[7 * Ksz + n];
    const float p16r = consts[8 * Ksz + n], p16i = consts[9 * Ksz + n];
    const int e = 3 - lg;
    const float b1r = (e & 1) ? p4r : 1.f, b1i = (e & 1) ? p4i : 0.f;
    const float b2r = (e & 2) ? p8r : 1.f, b2i = (e & 2) ? p8i : 0.f;
    float wr = b1r * b2r - b1i * b2i;
    float wi = b1r * b2i + b1i * b2r;
    float Sr = 0.f, Si = 0.f;
    #pragma unroll
    for (int mf = 1; mf >= 0; --mf) {
      float vr = wr, vi = wi;
      #pragma unroll
      for (int j = 3; j >= 0; --j) {
        const float u = acc[mf][f][j] + bv;
        U[(m0 + wm * 32 + mf * 16 + lg * 4 + j) * Ksz + n] = u;
        Sr = fmaf(u, vr, Sr);
        Si = fmaf(u, vi, Si);
        if (j) {
          float t_ = vr * ar_ - vi * ai_;
          vi = vr * ai_ + vi * ar_;
          vr = t_;
        }
      }
      if (mf) {
        float t_ = wr * p16r - wi * p16i;
        wi = wr * p16i + wi * p16r;
        wr = t_;
      }
    }
    Sr += __shfl_xor(Sr, 16); Si += __shfl_xor(Si, 16);
    Sr += __shfl_xor(Sr, 32); Si += __shfl_xor(Si, 32);
    if (lg == 0) {
      float pr = Sr, pi = Si;
      if (wm == 0) {
        const float p32r = consts[10 * Ksz + n], p32i = consts[11 * Ksz + n];
        pr = Sr * p32r - Si * p32i;
        pi = Sr * p32i + Si * p32r;
      }
      scratch[wm * 256 + n] = make_float2(pr, pi);
    }
  }
  __syncthreads();
  if (wm == 0 && lg == 0) {
    #pragma unroll
    for (int f = 0; f < 8; ++f) {
      const int n = wn * 128 + f * 16 + lr;
      float2 a0 = scratch[n], a1 = scratch[256 + n];
      ((float2*)carry)[(size_t)blockIdx.x * Ksz + n] =
          make_float2(a0.x + a1.x, a0.y + a1.y);
    }
  }
}

// --------- scan pass 2: exclusive prefix over chunks (A = a^64) ------------
__global__ __launch_bounds__(64) void scan_prefix(
    const float* __restrict__ consts, const float* __restrict__ carry,
    float* __restrict__ prefix) {
  const int k = blockIdx.y * 64 + threadIdx.x;
  const int b = blockIdx.x;
  const float Ar = consts[2 * Ksz + k], Ai = consts[3 * Ksz + k];
  const float2* cp = (const float2*)carry;
  float2* pp = (float2*)prefix;
  float c = 0.f, s = 0.f;
  for (int m = 0; m < NCH; ++m) {
    const size_t idx = (size_t)(b * NCH + m) * Ksz + k;
    pp[idx] = make_float2(c, s);
    float2 L = cp[idx];
    float cn = fmaf(Ar, c, fmaf(-Ai, s, L.x));
    float sn = fmaf(Ai, c, fmaf(Ar, s, L.y));
    c = cn; s = sn;
  }
}

// --------- scan pass 3: rescan chunk from true carry, write output ---------
__global__ __launch_bounds__(256) void scan_final(
    const float* __restrict__ U, const float* __restrict__ consts,
    const float* __restrict__ prefix, float* __restrict__ out) {
  const int k = threadIdx.x;
  const int bm = blockIdx.x;
  const float ar = consts[k], ai = consts[Ksz + k];
  float2 w = ((const float2*)prefix)[(size_t)bm * Ksz + k];
  float c = w.x, s = w.y;
  const float* up = U + (size_t)bm * (CHUNK * Ksz) + k;
  float* op = out + (size_t)bm * (CHUNK * 2 * Ksz);
  #pragma unroll 4
  for (int t = 0; t < CHUNK; ++t) {
    float u = up[(size_t)t * Ksz];
    float cn = fmaf(ar, c, fmaf(-ai, s, u));
    s = fmaf(ai, c, ar * s);
    c = cn;
    op[(size_t)t * 2 * Ksz + k] = c;
    op[(size_t)t * 2 * Ksz + Ksz + k] = s;
  }
}

extern "C" void kernel_launch(void* const* d_in, const int* in_sizes, int n_in,
                              void* d_out, int out_size, void* d_ws, size_t ws_size,
                              hipStream_t stream) {
  const float* x    = (const float*)d_in[0];
  const float* srr  = (const float*)d_in[1];
  const float* sim  = (const float*)d_in[2];
  const float* traw = (const float*)d_in[3];
  const float* W    = (const float*)d_in[4];
  const float* bias = (const float*)d_in[5];
  float* out = (float*)d_out;

  // ws layout (floats): consts[4096] | U[16777216] | carry[524288] |
  //   prefix[524288] | WfH[65536] | WfL[65536] | partial_v[8192] | wv[256]
  float* wsf    = (float*)d_ws;
  float* consts = wsf;
  float* U      = wsf + 4096;
  float* carry  = U + (size_t)Msz * Ksz;
  float* prefix = carry + (size_t)2 * Bsz * NCH * Ksz;
  unsigned int* WfH = (unsigned int*)(prefix + (size_t)2 * Bsz * NCH * Ksz);
  unsigned int* WfL = WfH + 65536;
  float* partial_v  = (float*)(WfL + 65536);
  float* wv         = partial_v + 16 * Dsz;

  prep1_kernel<<<16, 512, 0, stream>>>(W, partial_v);
  prep2_kernel<<<64, 512, 0, stream>>>(W, partial_v, wv);
  prep3_kernel<<<1, 256, 0, stream>>>(srr, sim, traw, wv, consts);
  wpack_kernel<<<256, 64, 0, stream>>>(W, consts, WfH, WfL);
  gemm_mfma<<<Msz / 64, 256, 0, stream>>>(x, WfH, WfL, bias, consts, U, carry);
  scan_prefix<<<dim3(Bsz, Ksz / 64), 64, 0, stream>>>(consts, carry, prefix);
  scan_final<<<Bsz * NCH, Ksz, 0, stream>>>(U, consts, prefix, out);
}

// Round 10
// 113.595 us; speedup vs baseline: 2.0745x; 1.2906x over previous
//
#include <hip/hip_runtime.h>

#define Bsz 16
#define Tsz 4096
#define Dsz 512
#define Ksz 256
#define Msz (Bsz * Tsz)      // 65536
#define CHUNK 64
#define NCH (Tsz / CHUNK)    // 64

typedef __attribute__((ext_vector_type(8))) short short8;
typedef __attribute__((ext_vector_type(4))) float f32x4;

// ---------------- threefry2x32 (key = (0, 42)) — matches JAX exactly -------
__device__ __forceinline__ unsigned int rotl32(unsigned int x, int d) {
  return (x << d) | (x >> (32 - d));
}

__device__ void threefry_pair(unsigned int c0, unsigned int c1,
                              unsigned int& o0, unsigned int& o1) {
  const unsigned int k0 = 0u, k1 = 42u;
  const unsigned int k2 = k0 ^ k1 ^ 0x1BD11BDAu;
  unsigned int x0 = c0 + k0;
  unsigned int x1 = c1 + k1;
#define TF_ROUND(r) { x0 += x1; x1 = rotl32(x1, (r)); x1 ^= x0; }
  TF_ROUND(13) TF_ROUND(15) TF_ROUND(26) TF_ROUND(6)
  x0 += k1; x1 += k2 + 1u;
  TF_ROUND(17) TF_ROUND(29) TF_ROUND(16) TF_ROUND(24)
  x0 += k2; x1 += k0 + 2u;
  TF_ROUND(13) TF_ROUND(15) TF_ROUND(26) TF_ROUND(6)
  x0 += k0; x1 += k1 + 3u;
  TF_ROUND(17) TF_ROUND(29) TF_ROUND(16) TF_ROUND(24)
  x0 += k1; x1 += k2 + 4u;
  TF_ROUND(13) TF_ROUND(15) TF_ROUND(26) TF_ROUND(6)
  x0 += k2; x1 += k0 + 5u;
#undef TF_ROUND
  o0 = x0; o1 = x1;
}

// XLA ErfInv32 polynomial (math.cc)
__device__ float erfinv32(float x) {
  float w = -log1pf(-x * x);
  float p;
  if (w < 5.f) {
    w -= 2.5f;
    p = 2.81022636e-08f;
    p = fmaf(p, w, 3.43273939e-07f);
    p = fmaf(p, w, -3.5233877e-06f);
    p = fmaf(p, w, -4.39150654e-06f);
    p = fmaf(p, w, 0.00021858087f);
    p = fmaf(p, w, -0.00125372503f);
    p = fmaf(p, w, -0.00417768164f);
    p = fmaf(p, w, 0.246640727f);
    p = fmaf(p, w, 1.50140941f);
  } else {
    w = sqrtf(w) - 3.f;
    p = -0.000200214257f;
    p = fmaf(p, w, 0.000100950558f);
    p = fmaf(p, w, 0.00134934322f);
    p = fmaf(p, w, -0.00367342844f);
    p = fmaf(p, w, 0.00573950773f);
    p = fmaf(p, w, -0.0076224613f);
    p = fmaf(p, w, 0.00943887047f);
    p = fmaf(p, w, 1.00167406f);
    p = fmaf(p, w, 2.83297682f);
  }
  return p * x;
}

// JAX: bits -> uniform[-0.99999994, 1) -> sqrt(2)*erfinv
__device__ float bits_to_normal(unsigned int bits) {
  unsigned int fb = (bits >> 9) | 0x3f800000u;
  float f = __uint_as_float(fb) - 1.0f;   // [0,1)
  const float lo = -0.99999994f;          // nextafter(-1, 0) in f32
  float u = f * 2.0f + lo;                // hi - lo rounds to exactly 2.0f
  u = fmaxf(lo, u);
  return 1.41421356f * erfinv32(u);
}

__device__ float block_sum_512(float v, float* s_red) {
  #pragma unroll
  for (int o = 32; o > 0; o >>= 1) v += __shfl_down(v, o);
  const int lane = threadIdx.x & 63, wid = threadIdx.x >> 6;
  if (lane == 0) s_red[wid] = v;
  __syncthreads();
  float r = 0.f;
  #pragma unroll
  for (int i = 0; i < 8; ++i) r += s_red[i];
  __syncthreads();
  return r;
}

__device__ __forceinline__ unsigned int bf16rne(float f) {
  unsigned int u = __float_as_uint(f);
  return (u + 0x7FFFu + ((u >> 16) & 1u)) >> 16;
}

// --------- prep1 (16 blocks x 512): partial_v[b][d] = sum_k W[k][d]*u0n[k] --
__global__ __launch_bounds__(512) void prep1_kernel(
    const float* __restrict__ W, float* __restrict__ partial_v) {
  __shared__ float s_u0[Ksz];
  __shared__ float s_red[8];
  const int tid = threadIdx.x;
  if (tid < 128) {
    unsigned int y0, y1;
    threefry_pair((unsigned int)tid, (unsigned int)(tid + 128), y0, y1);
    s_u0[tid] = bits_to_normal(y0);
    s_u0[tid + 128] = bits_to_normal(y1);
  }
  __syncthreads();
  float val = (tid < Ksz) ? s_u0[tid] * s_u0[tid] : 0.f;
  float ss = block_sum_512(val, s_red);
  float inv = 1.f / fmaxf(sqrtf(ss), 1e-7f);

  const int k0 = blockIdx.x * 16;
  float acc = 0.f;
  #pragma unroll
  for (int kk = 0; kk < 16; ++kk)
    acc = fmaf(W[(size_t)(k0 + kk) * Dsz + tid], s_u0[k0 + kk], acc);
  partial_v[blockIdx.x * Dsz + tid] = acc * inv;
}

// --------- prep2 (64 blocks x 512): v = normalize(sum partials); wv rows ---
__global__ __launch_bounds__(512) void prep2_kernel(
    const float* __restrict__ W, const float* __restrict__ partial_v,
    float* __restrict__ wv) {
  __shared__ float s_v[Dsz];
  __shared__ float s_red[8];
  __shared__ float s_p[8];
  const int tid = threadIdx.x;
  float acc = 0.f;
  #pragma unroll
  for (int b = 0; b < 16; ++b) acc += partial_v[b * Dsz + tid];
  float ssv = block_sum_512(acc * acc, s_red);
  float invv = 1.f / fmaxf(sqrtf(ssv), 1e-7f);
  s_v[tid] = acc * invv;
  __syncthreads();

  const int k = blockIdx.x * 4 + (tid >> 7);
  const int sub = tid & 127;
  const float* wr = W + (size_t)k * Dsz;
  float p = 0.f;
  #pragma unroll
  for (int j = sub; j < Dsz; j += 128) p = fmaf(wr[j], s_v[j], p);
  #pragma unroll
  for (int o = 32; o > 0; o >>= 1) p += __shfl_down(p, o);
  const int lane = tid & 63, wid = tid >> 6;
  if (lane == 0) s_p[wid] = p;
  __syncthreads();
  if (tid < 4) wv[blockIdx.x * 4 + tid] = s_p[2 * tid] + s_p[2 * tid + 1];
}

// --------- prep3 (1 block x 256): sigma + all per-k constants --------------
// consts layout (floats): [0]=ar [K]=ai [2K]=A64r [3K]=A64i [4K]=P4r [5K]=P4i
//   [6K]=P8r [7K]=P8i [8K]=P16r [9K]=P16i [10K]=P32r [11K]=P32i [12K]=inv_sigma
__global__ __launch_bounds__(256) void prep3_kernel(
    const float* __restrict__ s_real_raw, const float* __restrict__ s_imag,
    const float* __restrict__ tau_raw, const float* __restrict__ wv,
    float* __restrict__ consts) {
  __shared__ float s_p[4];
  const int tid = threadIdx.x;
  float v = wv[tid];
  float v2 = v * v;
  #pragma unroll
  for (int o = 32; o > 0; o >>= 1) v2 += __shfl_down(v2, o);
  const int lane = tid & 63, wid = tid >> 6;
  if (lane == 0) s_p[wid] = v2;
  __syncthreads();
  float sswv = s_p[0] + s_p[1] + s_p[2] + s_p[3];
  float sigma = sswv / fmaxf(sqrtf(sswv), 1e-7f);
  if (tid == 0) consts[12 * Ksz] = 1.f / sigma;

  float tr = tau_raw[0];
  float tau = fmaxf(tr, 0.f) + log1pf(expf(-fabsf(tr))) + 1e-3f;
  float srr = s_real_raw[tid];
  float sp = fmaxf(srr, 0.f) + log1pf(expf(-fabsf(srr)));
  float alpha0 = (sp + 1e-6f) * tau;
  float omega0 = s_imag[tid] * tau;
  const float dt = 1.f / 4095.f;
  float ad = alpha0 * dt, an = omega0 * dt;
  consts[tid]            = expf(-ad) * cosf(an);
  consts[Ksz + tid]      = expf(-ad) * sinf(an);
  consts[2 * Ksz + tid]  = expf(-ad * 64.f) * cosf(an * 64.f);
  consts[3 * Ksz + tid]  = expf(-ad * 64.f) * sinf(an * 64.f);
  consts[4 * Ksz + tid]  = expf(-ad * 4.f) * cosf(an * 4.f);
  consts[5 * Ksz + tid]  = expf(-ad * 4.f) * sinf(an * 4.f);
  consts[6 * Ksz + tid]  = expf(-ad * 8.f) * cosf(an * 8.f);
  consts[7 * Ksz + tid]  = expf(-ad * 8.f) * sinf(an * 8.f);
  consts[8 * Ksz + tid]  = expf(-ad * 16.f) * cosf(an * 16.f);
  consts[9 * Ksz + tid]  = expf(-ad * 16.f) * sinf(an * 16.f);
  consts[10 * Ksz + tid] = expf(-ad * 32.f) * cosf(an * 32.f);
  consts[11 * Ksz + tid] = expf(-ad * 32.f) * sinf(an * 32.f);
}

// --------- wpack: W/sigma -> bf16 h/l in MFMA B-fragment order -------------
__global__ __launch_bounds__(64) void wpack_kernel(
    const float* __restrict__ W, const float* __restrict__ consts,
    unsigned int* __restrict__ WfH, unsigned int* __restrict__ WfL) {
  const int kb = blockIdx.x >> 4;
  const int nb = blockIdx.x & 15;
  const int lane = threadIdx.x;
  const int lr = lane & 15, lg = lane >> 4;
  const float inv_sigma = consts[12 * Ksz];
  const float* src = W + (size_t)(nb * 16 + lr) * Dsz + kb * 32 + lg * 8;
  float v[8];
  *(float4*)&v[0] = *(const float4*)src;
  *(float4*)&v[4] = *(const float4*)(src + 4);
  unsigned int hh[4], ll[4];
  #pragma unroll
  for (int i = 0; i < 4; ++i) {
    float v0 = v[2 * i] * inv_sigma, v1 = v[2 * i + 1] * inv_sigma;
    unsigned int u0 = __float_as_uint(v0);
    unsigned int u1 = __float_as_uint(v1);
    hh[i] = (u0 >> 16) | (u1 & 0xFFFF0000u);
    float r0 = v0 - __uint_as_float(u0 & 0xFFFF0000u);
    float r1 = v1 - __uint_as_float(u1 & 0xFFFF0000u);
    ll[i] = bf16rne(r0) | (bf16rne(r1) << 16);
  }
  const size_t off = (size_t)blockIdx.x * 256 + lane * 4;   // in uints
  *(int4*)(WfH + off) = *(int4*)hh;
  *(int4*)(WfL + off) = *(int4*)ll;
}

// --------- MFMA GEMM + fused chunk-scan carry ------------------------------
// BM=128 (= 2 scan chunks), BN=256, BK=32. 512 threads = 8 waves (2m x 4n):
// wave owns 64 rows x 64 cols -> 48 MFMA/phase (round-5's amortization) AND
// 2 waves/SIMD (round-8's TLP). Schedule = round-5's proven B-reg-dbuf +
// LDS dbuf + single lgkm-drain barrier per phase. U stored bf16 (RNE).
// Epilogue: round-5 per-wave 64-row carry, chunk index = 2*blockIdx + wm.
__global__ __launch_bounds__(512, 2) void gemm_mfma(
    const float* __restrict__ X, const unsigned int* __restrict__ WfH,
    const unsigned int* __restrict__ WfL, const float* __restrict__ bias,
    const float* __restrict__ consts, unsigned short* __restrict__ U,
    float* __restrict__ carry) {
  __shared__ unsigned int ldsA[2][4096];   // 2 x 16KB: 128 rows x [64B h|64B l]

  const int tid = threadIdx.x;
  const size_t m0 = (size_t)blockIdx.x * 128;

  // A staging: thread -> (row sr = tid>>2, k-chunk sc = (tid&3)*8 floats)
  const int sr = tid >> 2;              // 0..127
  const int sc = (tid & 3) * 8;
  const float* gx = X + (m0 + sr) * Dsz + sc;
  const int swz = (sr & 7) << 4;
  const int aoff_h = sr * 128 + ((sc * 2) ^ swz);
  const int aoff_l = sr * 128 + ((64 + sc * 2) ^ swz);

  const int lane = tid & 63;
  const int wid = tid >> 6;             // 0..7
  const int wm = wid >> 2;              // 0..1 -> rows wm*64
  const int wn = wid & 3;               // 0..3 -> cols wn*64
  const int lr = lane & 15;
  const int lg = lane >> 4;

  float xaA[8], xaB[8];
  #define LOAD_A(dst, kb) do {                             \
    const float* p = gx + (kb) * 32;                       \
    *(float4*)&dst[0] = *(const float4*)p;                 \
    *(float4*)&dst[4] = *(const float4*)(p + 4);           \
  } while (0)

  const char* const wfh = (const char*)WfH + (size_t)wn * 4096 + lane * 16;
  const char* const wfl = (const char*)WfL + (size_t)wn * 4096 + lane * 16;

  short8 bhA[4], blA[4], bhB[4], blB[4];
  #define LOAD_B(bh_, bl_, kb) do {                                          \
    const size_t tb = (size_t)(kb) * 16384;                                  \
    _Pragma("unroll")                                                        \
    for (int f = 0; f < 4; ++f) {                                            \
      bh_[f] = *(const short8*)(wfh + tb + (size_t)f * 1024);                \
      bl_[f] = *(const short8*)(wfl + tb + (size_t)f * 1024);                \
    }                                                                        \
  } while (0)

  #define CONVERT_STORE(xa, buf) do {                                        \
    char* const Ab_ = (char*)ldsA[(buf)];                                    \
    unsigned int hh[4], llw[4];                                              \
    _Pragma("unroll")                                                        \
    for (int i = 0; i < 4; ++i) {                                            \
      float v0 = xa[2 * i], v1 = xa[2 * i + 1];                              \
      unsigned int u0 = __float_as_uint(v0);                                 \
      unsigned int u1 = __float_as_uint(v1);                                 \
      hh[i] = (u0 >> 16) | (u1 & 0xFFFF0000u);                               \
      float r0 = v0 - __uint_as_float(u0 & 0xFFFF0000u);                     \
      float r1 = v1 - __uint_as_float(u1 & 0xFFFF0000u);                     \
      llw[i] = bf16rne(r0) | (bf16rne(r1) << 16);                            \
    }                                                                        \
    *(int4*)(Ab_ + aoff_h) = *(int4*)hh;                                     \
    *(int4*)(Ab_ + aoff_l) = *(int4*)llw;                                    \
  } while (0)

  short8 ah[4], al[4];
  #define DS_READ(buf) do {                                                  \
    const char* const Ab_ = (const char*)ldsA[(buf)];                        \
    _Pragma("unroll")                                                        \
    for (int f = 0; f < 4; ++f) {                                            \
      const int r = wm * 64 + f * 16 + lr;                                   \
      const int sz = (r & 7) << 4;                                           \
      ah[f] = *(const short8*)(Ab_ + r * 128 + ((lg * 16) ^ sz));            \
      al[f] = *(const short8*)(Ab_ + r * 128 + ((64 + lg * 16) ^ sz));       \
    }                                                                        \
  } while (0)

  f32x4 acc[4][4];
  #pragma unroll
  for (int i = 0; i < 4; ++i)
    #pragma unroll
    for (int j = 0; j < 4; ++j) acc[i][j] = (f32x4)(0.f);

  #define MFMA48(bh_, bl_) do {                                              \
    _Pragma("unroll")                                                        \
    for (int mf = 0; mf < 4; ++mf)                                           \
      _Pragma("unroll")                                                      \
      for (int nf = 0; nf < 4; ++nf)                                         \
        acc[mf][nf] = __builtin_amdgcn_mfma_f32_16x16x32_bf16(               \
            ah[mf], bh_[nf], acc[mf][nf], 0, 0, 0);                          \
    _Pragma("unroll")                                                        \
    for (int mf = 0; mf < 4; ++mf)                                           \
      _Pragma("unroll")                                                      \
      for (int nf = 0; nf < 4; ++nf)                                         \
        acc[mf][nf] = __builtin_amdgcn_mfma_f32_16x16x32_bf16(               \
            ah[mf], bl_[nf], acc[mf][nf], 0, 0, 0);                          \
    _Pragma("unroll")                                                        \
    for (int mf = 0; mf < 4; ++mf)                                           \
      _Pragma("unroll")                                                      \
      for (int nf = 0; nf < 4; ++nf)                                         \
        acc[mf][nf] = __builtin_amdgcn_mfma_f32_16x16x32_bf16(               \
            al[mf], bh_[nf], acc[mf][nf], 0, 0, 0);                          \
  } while (0)

  #define SYNC() do {                                                        \
    asm volatile("s_waitcnt lgkmcnt(0)" ::: "memory");                       \
    __builtin_amdgcn_s_barrier();                                            \
    __builtin_amdgcn_sched_barrier(0);                                       \
  } while (0)

  // prologue (round-5): raw A 2-deep, B 1-ahead
  LOAD_A(xaA, 0);
  LOAD_A(xaB, 1);
  LOAD_B(bhA, blA, 0);

  #define BODY(kb, xa, bhC, blC, bhN, blN) do {                              \
    char* const Ab = (char*)ldsA[(kb) & 1]; (void)Ab;                        \
    if ((kb) + 1 < 16) LOAD_B(bhN, blN, (kb) + 1);   /* issue B early */     \
    CONVERT_STORE(xa, (kb) & 1);                                             \
    if ((kb) + 2 < 16) LOAD_A(xa, (kb) + 2);         /* 2-deep A */          \
    SYNC();                                                                  \
    DS_READ((kb) & 1);                                                       \
    MFMA48(bhC, blC);                                                        \
  } while (0)

  for (int kb = 0; kb < 16; kb += 2) {
    BODY(kb,     xaA, bhA, blA, bhB, blB);
    BODY(kb + 1, xaB, bhB, blB, bhA, blA);
  }
  #undef BODY
  #undef SYNC
  #undef MFMA48
  #undef DS_READ
  #undef CONVERT_STORE
  #undef LOAD_B
  #undef LOAD_A

  // ---- epilogue: bf16 U store + fused 64-row chunk carry ----
  // wave's rows = one chunk (index 2*blockIdx+wm): t = mf*16 + lg*4 + j,
  // weight a^{63-t} = P4^{3-lg} * P16^{3-mf} * a^{3-j}
  #pragma unroll
  for (int nf = 0; nf < 4; ++nf) {
    const int n = wn * 64 + nf * 16 + lr;
    const float bv = bias[n];
    const float ar_ = consts[n],           ai_ = consts[Ksz + n];
    const float p4r = consts[4 * Ksz + n], p4i = consts[5 * Ksz + n];
    const float p8r = consts[6 * Ksz + n], p8i = consts[7 * Ksz + n];
    const float p16r = consts[8 * Ksz + n], p16i = consts[9 * Ksz + n];
    const int e = 3 - lg;
    const float b1r = (e & 1) ? p4r : 1.f, b1i = (e & 1) ? p4i : 0.f;
    const float b2r = (e & 2) ? p8r : 1.f, b2i = (e & 2) ? p8i : 0.f;
    float wr = b1r * b2r - b1i * b2i;
    float wi = b1r * b2i + b1i * b2r;
    float Sr = 0.f, Si = 0.f;
    #pragma unroll
    for (int mf = 3; mf >= 0; --mf) {
      float vr = wr, vi = wi;
      #pragma unroll
      for (int j = 3; j >= 0; --j) {
        const float u = acc[mf][nf][j] + bv;
        U[(m0 + wm * 64 + mf * 16 + lg * 4 + j) * Ksz + n] =
            (unsigned short)bf16rne(u);
        Sr = fmaf(u, vr, Sr);
        Si = fmaf(u, vi, Si);
        if (j) {
          float t_ = vr * ar_ - vi * ai_;
          vi = vr * ai_ + vi * ar_;
          vr = t_;
        }
      }
      if (mf) {
        float t_ = wr * p16r - wi * p16i;
        wi = wr * p16i + wi * p16r;
        wr = t_;
      }
    }
    Sr += __shfl_xor(Sr, 16); Si += __shfl_xor(Si, 16);
    Sr += __shfl_xor(Sr, 32); Si += __shfl_xor(Si, 32);
    if (lg == 0)
      ((float2*)carry)[(size_t)(blockIdx.x * 2 + wm) * Ksz + n] =
          make_float2(Sr, Si);
  }
}

// --------- scan pass 2: exclusive prefix over chunks (A = a^64) ------------
__global__ __launch_bounds__(64) void scan_prefix(
    const float* __restrict__ consts, const float* __restrict__ carry,
    float* __restrict__ prefix) {
  const int k = blockIdx.y * 64 + threadIdx.x;
  const int b = blockIdx.x;
  const float Ar = consts[2 * Ksz + k], Ai = consts[3 * Ksz + k];
  const float2* cp = (const float2*)carry;
  float2* pp = (float2*)prefix;
  float c = 0.f, s = 0.f;
  for (int m = 0; m < NCH; ++m) {
    const size_t idx = (size_t)(b * NCH + m) * Ksz + k;
    pp[idx] = make_float2(c, s);
    float2 L = cp[idx];
    float cn = fmaf(Ar, c, fmaf(-Ai, s, L.x));
    float sn = fmaf(Ai, c, fmaf(Ar, s, L.y));
    c = cn; s = sn;
  }
}

// --------- scan pass 3: rescan chunk from true carry, write output ---------
__global__ __launch_bounds__(256) void scan_final(
    const unsigned short* __restrict__ U, const float* __restrict__ consts,
    const float* __restrict__ prefix, float* __restrict__ out) {
  const int k = threadIdx.x;
  const int bm = blockIdx.x;
  const float ar = consts[k], ai = consts[Ksz + k];
  float2 w = ((const float2*)prefix)[(size_t)bm * Ksz + k];
  float c = w.x, s = w.y;
  const unsigned short* up = U + (size_t)bm * (CHUNK * Ksz) + k;
  float* op = out + (size_t)bm * (CHUNK * 2 * Ksz);
  #pragma unroll 4
  for (int t = 0; t < CHUNK; ++t) {
    float u = __uint_as_float((unsigned int)up[(size_t)t * Ksz] << 16);
    float cn = fmaf(ar, c, fmaf(-ai, s, u));
    s = fmaf(ai, c, ar * s);
    c = cn;
    op[(size_t)t * 2 * Ksz + k] = c;
    op[(size_t)t * 2 * Ksz + Ksz + k] = s;
  }
}

extern "C" void kernel_launch(void* const* d_in, const int* in_sizes, int n_in,
                              void* d_out, int out_size, void* d_ws, size_t ws_size,
                              hipStream_t stream) {
  const float* x    = (const float*)d_in[0];
  const float* srr  = (const float*)d_in[1];
  const float* sim  = (const float*)d_in[2];
  const float* traw = (const float*)d_in[3];
  const float* W    = (const float*)d_in[4];
  const float* bias = (const float*)d_in[5];
  float* out = (float*)d_out;

  // ws layout (floats): consts[4096] | U(bf16: Msz*Ksz ushorts = 8388608 fl)
  //   | carry[524288] | prefix[524288] | WfH[65536] | WfL[65536]
  //   | partial_v[8192] | wv[256]
  float* wsf    = (float*)d_ws;
  float* consts = wsf;
  unsigned short* U = (unsigned short*)(wsf + 4096);
  float* carry  = wsf + 4096 + 8388608;
  float* prefix = carry + (size_t)2 * Bsz * NCH * Ksz;
  unsigned int* WfH = (unsigned int*)(prefix + (size_t)2 * Bsz * NCH * Ksz);
  unsigned int* WfL = WfH + 65536;
  float* partial_v  = (float*)(WfL + 65536);
  float* wv         = partial_v + 16 * Dsz;

  prep1_kernel<<<16, 512, 0, stream>>>(W, partial_v);
  prep2_kernel<<<64, 512, 0, stream>>>(W, partial_v, wv);
  prep3_kernel<<<1, 256, 0, stream>>>(srr, sim, traw, wv, consts);
  wpack_kernel<<<256, 64, 0, stream>>>(W, consts, WfH, WfL);
  gemm_mfma<<<Msz / 128, 512, 0, stream>>>(x, WfH, WfL, bias, consts, U, carry);
  scan_prefix<<<dim3(Bsz, Ksz / 64), 64, 0, stream>>>(consts, carry, prefix);
  scan_final<<<Bsz * NCH, Ksz, 0, stream>>>(U, consts, prefix, out);
}